// Round 5
// baseline (249.310 us; speedup 1.0000x reference)
//
#include <hip/hip_runtime.h>
#include <math.h>

#define CI 12
#define NHID 15
#define NBLK 6144                 // 8*3*16*16 image blocks of 32x32
#define NPIX (NBLK * 1024)

typedef float  f32x4 __attribute__((ext_vector_type(4)));
typedef int    i32x4 __attribute__((ext_vector_type(4)));
typedef short  s16x8 __attribute__((ext_vector_type(8)));

// f32 -> bf16 trunc pack via byte-perm: dst = hi16(hi):hi16(lo)
static __device__ __forceinline__ int bfpack(float lo, float hi) {
    return (int)__builtin_amdgcn_perm(__float_as_uint(hi), __float_as_uint(lo),
                                      0x07060302u);
}
// f32 -> bf16 RNE (weights, cold path)
static __device__ __forceinline__ unsigned bfrne(float x) {
    unsigned u = __float_as_uint(x);
    u += 0x7FFFu + ((u >> 16) & 1u);
    return u >> 16;
}
static __device__ __forceinline__ int bfpack_rne(float lo, float hi) {
    return (int)((bfrne(hi) << 16) | bfrne(lo));
}
static __device__ __forceinline__ float leaky(float x) {
    return fmaxf(x, 0.01f * x);
}
static __device__ __forceinline__ f32x4 mfma16(i32x4 a, i32x4 b, f32x4 c) {
    return __builtin_amdgcn_mfma_f32_16x16x32_bf16(
        __builtin_bit_cast(s16x8, a), __builtin_bit_cast(s16x8, b), c, 0, 0, 0);
}

// Sparse-K layout: channel c=4q+r at k-slot 8q+r (q=0..2); bias at k=4; all
// other k-slots carry zero weights, so the MFMA C-layout output (lane 16q+t
// holds channels 4q..4q+3 of pixel t) IS the next layer's B-frag. No shuffles.
__global__ __launch_bounds__(256, 4) void codec_main(
    const float* __restrict__ x,
    const float* __restrict__ Wh,   // [15][12][12]
    const float* __restrict__ bh,   // [15][12]
    const float* __restrict__ Wo,   // [12]
    const float* __restrict__ bo,   // [1]
    float* __restrict__ out,        // [1 + NPIX]
    float* __restrict__ loss_acc)   // [1] pre-zeroed
{
    __shared__ float tile[36 * 37]; // 32x32 + 2-halo, +1 col pad
    __shared__ float stage[4][256]; // per-wave delta staging for coalesced store
    __shared__ float wsum[4];

    const int n    = blockIdx.x;
    const int tid  = threadIdx.x;   // 0..255
    const int lane = tid & 63;
    const int wv   = tid >> 6;      // wave 0..3
    const int t    = lane & 15;     // pixel role / weight-row role
    const int q    = lane >> 4;     // quad 0..3

    // ---- stage image block into LDS (zero halo = per-block zero padding) ----
    {
        const int col = tid & 31;
        const int r0  = tid >> 5;   // 0..7
        #pragma unroll
        for (int i = 0; i < 6; ++i) {
            int idx = tid + i * 256;
            if (idx < 36 * 37) tile[idx] = 0.0f;
        }
        __syncthreads();
        const int bc  = n >> 8;
        const int blk = n & 255;
        const int by  = blk >> 4;
        const int bx  = blk & 15;
        #pragma unroll
        for (int p = 0; p < 4; ++p) {
            const int row = r0 + 8 * p;
            tile[(row + 2) * 37 + col + 2] =
                x[((size_t)bc * 512 + (size_t)(by * 32 + row)) * 512
                  + (size_t)(bx * 32 + col)];
        }
        __syncthreads();
    }

    // ---- weight A-frags: lane 16q+t holds A[m=t][k=8q+j], j=0..7 ----
    // j=0..3 <- W[t][4q+j]; (q==0,j==4) <- bias; else 0
    i32x4 wA[NHID];
    i32x4 wHd;
    const bool wok = (t < CI) && (q < 3);
    #pragma unroll
    for (int l = 0; l < NHID; ++l) {
        float4 w = {0.f, 0.f, 0.f, 0.f};
        float  b = 0.f;
        if (wok) w = *(const float4*)(Wh + l * (CI * CI) + t * CI + 4 * q);
        if (wok && q == 0) b = bh[l * CI + t];
        wA[l] = (i32x4){ bfpack_rne(w.x, w.y), bfpack_rne(w.z, w.w),
                         bfpack_rne(b, 0.f), 0 };
    }
    {
        float4 w = {0.f, 0.f, 0.f, 0.f};
        float  b = 0.f;
        if (t == 0 && q < 3) w = *(const float4*)(Wo + 4 * q);
        if (t == 0 && q == 0) b = bo[0];
        wHd = (i32x4){ bfpack_rne(w.x, w.y), bfpack_rne(w.z, w.w),
                       bfpack_rne(b, 0.f), 0 };
    }
    // pin weights to arch VGPRs (avoid AGPR round-trips / rematerialization)
    #pragma unroll
    for (int l = 0; l < NHID; ++l) asm volatile("" : "+v"(wA[l]));
    asm volatile("" : "+v"(wHd));

    // ---- per-lane feature offsets (elements): channel c=4q+r at (dy,dx) ----
    // r0:{-76,-72,-36,0} r1:{-75,-39,-35,0} r2:{-74,-38,-2,0} r3:{-73,-37,-1,0}
    const int sh8  = q * 8;
    const int off0 = (int)(signed char)((0x00DCB8B4u >> sh8) & 0xFFu);
    const int off1 = (int)(signed char)((0x00DDD9B5u >> sh8) & 0xFFu);
    const int off2 = (int)(signed char)((0x00FEDAB6u >> sh8) & 0xFFu);
    const int off3 = (int)(signed char)((0x00FFDBB7u >> sh8) & 0xFFu);

    // element indices for row y0 = wv*8, x-half A (px = t); half B = +16 (imm)
    const int base = (wv * 8 + 2) * 37 + (t + 2);
    int e0 = base + off0;
    int e1 = base + off1;
    int e2 = base + off2;
    int e3 = base + off3;
    int ev = base;

    const int biasreg = (q == 0) ? 0x00003F80 : 0;   // k=4 slot = bf16(1.0)
    const f32x4 zero4 = {0.f, 0.f, 0.f, 0.f};

    float d2 = 0.0f;
    #pragma unroll 1
    for (int yi = 0; yi < 8; ++yi) {
        // feature loads for both halves (+16 folds into ds_read imm offset)
        const float fA0 = tile[e0], fB0 = tile[e0 + 16];
        const float fA1 = tile[e1], fB1 = tile[e1 + 16];
        const float fA2 = tile[e2], fB2 = tile[e2 + 16];
        const float fA3 = tile[e3], fB3 = tile[e3 + 16];
        const float vA  = tile[ev], vB  = tile[ev + 16];

        i32x4 BA = (i32x4){ bfpack(fA0, fA1), bfpack(fA2, fA3), biasreg, 0 };
        i32x4 BB = (i32x4){ bfpack(fB0, fB1), bfpack(fB2, fB3), biasreg, 0 };

        f32x4 aA, aB;
        #pragma unroll
        for (int l = 0; l < NHID; ++l) {
            aA = mfma16(wA[l], BA, zero4);
            aB = mfma16(wA[l], BB, zero4);
            BA[0] = bfpack(leaky(aA[0]), leaky(aA[1]));
            BA[1] = bfpack(leaky(aA[2]), leaky(aA[3]));
            BB[0] = bfpack(leaky(aB[0]), leaky(aB[1]));
            BB[1] = bfpack(leaky(aB[2]), leaky(aB[3]));
        }
        aA = mfma16(wHd, BA, zero4);
        aB = mfma16(wHd, BB, zero4);

        if (lane < 16) {                     // row 0 of D = prediction
            const float pA = fminf(fmaxf(aA[0], -1.0f), 1.0f);
            const float uA = vA - pA + 1.0f;
            const float dA = uA - ((uA < 2.0f) ? 1.0f : 3.0f); // fmod(u,2)-1
            const float pB = fminf(fmaxf(aB[0], -1.0f), 1.0f);
            const float uB = vB - pB + 1.0f;
            const float dB = uB - ((uB < 2.0f) ? 1.0f : 3.0f);
            stage[wv][yi * 32 + t]      = dA;
            stage[wv][yi * 32 + 16 + t] = dB;
            d2 = fmaf(dA, dA, fmaf(dB, dB, d2));
        }
        e0 += 37; e1 += 37; e2 += 37; e3 += 37; ev += 37;
    }

    // ---- coalesced delta store: wave's 256 floats = rows [8wv, 8wv+8) ----
    float* outp = out + 1 + (size_t)n * 1024 + wv * 256;
    #pragma unroll
    for (int j = 0; j < 4; ++j)
        outp[j * 64 + lane] = stage[wv][j * 64 + lane];

    // ---- loss reduction (d2 nonzero only in lanes 0..15) ----
    #pragma unroll
    for (int off = 8; off > 0; off >>= 1) d2 += __shfl_down(d2, off, 64);
    if (lane == 0) wsum[wv] = d2;
    __syncthreads();
    if (tid == 0) atomicAdd(loss_acc, wsum[0] + wsum[1] + wsum[2] + wsum[3]);
}

__global__ void codec_loss(const float* __restrict__ acc, float* __restrict__ out)
{
    out[0] = 255.0f * sqrtf(acc[0] / (float)NPIX);
}

extern "C" void kernel_launch(void* const* d_in, const int* in_sizes, int n_in,
                              void* d_out, int out_size, void* d_ws, size_t ws_size,
                              hipStream_t stream)
{
    const float* x  = (const float*)d_in[0];
    const float* Wh = (const float*)d_in[1];
    const float* bh = (const float*)d_in[2];
    const float* Wo = (const float*)d_in[3];
    const float* bo = (const float*)d_in[4];
    float* out = (float*)d_out;
    float* acc = (float*)d_ws;

    hipMemsetAsync(acc, 0, sizeof(float), stream);   // graph-capture safe
    codec_main<<<NBLK, 256, 0, stream>>>(x, Wh, bh, Wo, bo, out, acc);
    codec_loss<<<1, 1, 0, stream>>>(acc, out);
}